// Round 11
// baseline (130.730 us; speedup 1.0000x reference)
//
#include <hip/hip_runtime.h>
#include <math.h>

#define C_CLS   19
#define H_IN    97
#define W_IN    97
#define HW_IN   (H_IN * W_IN)
#define CHW_IN  (C_CLS * HW_IN)
#define H_OUT   769
#define W_OUT   769
#define N_BATCH 4
#define NROWS   (N_BATCH * H_OUT)    // 3076
#define NSLOT_R 195                  // half-run slots per row (97*2 + 1 clamp)
#define TOTTHR  (NROWS * NSLOT_R)    // 599,820
#define BLKT    64                   // ONE wave per block: no barriers ever
#define NBLK    ((TOTTHR + BLKT - 1) / BLKT)   // 9373
#define IGNORE_LBL 255
#define MIN_KEPT   100000
#define NHI     110
#define ACC_STRIDE 1024
#define NSETS   256                  // striped accumulator lines
#define SET_BASE 2048
#define NLL_THR 0.35667494f          // -ln(0.7)

__device__ const float c_class_w[C_CLS] = {
    0.8373f, 0.918f,  0.866f,  1.0345f, 1.0166f, 0.9969f, 0.9754f,
    1.0489f, 0.8786f, 1.0023f, 0.9539f, 0.9843f, 1.1116f, 0.9037f,
    1.0865f, 1.0955f, 1.0865f, 1.1529f, 1.0507f};

// ws layout (floats):
// [4..333] hist pred1 (cnt/sw/swnll, stride 110); [1028..1357] hist pred2
// [2048 + s*16 + k] striped set s (0=nv 1=w1 2=wlp1 3=cle1 4=w2 5=wlp2 6=cle2)

__global__ __launch_bounds__(BLKT, 6) void ohem_wave(
    const float* __restrict__ pred1, const float* __restrict__ pred2,
    const int* __restrict__ target, float* __restrict__ ws)
{
    const int tid  = threadIdx.x;
    const int gtid = blockIdx.x * BLKT + tid;
    const bool live = gtid < TOTTHR;

    int row  = min(gtid / NSLOT_R, NROWS - 1);
    int slot = gtid - row * NSLOT_R;          // may exceed 194 only when !live
    const int n = row / H_OUT;
    const int y = row - n * H_OUT;

    const float scl = (float)H_IN / (float)H_OUT;

    // ---- half-run geometry ----
    int col, xs_h, npx;
    float fx0, hstep;
    if (slot < 194) {
        col = slot >> 1;
        int xs = ((2 * col + 1) * 769 + 96) / 194;
        int xe = min(((2 * col + 3) * 769 + 96) / 194, 769);
        int half = slot & 1;
        xs_h = xs + half * 4;
        npx  = half ? max(xe - xs - 4, 0) : min(xe - xs, 4);
        fx0  = fmaf((float)xs_h + 0.5f, scl, -0.5f) - (float)col;
        hstep = scl;
    } else {                                  // slot==194: left clamp, fx=0
        col = 0; xs_h = 0; npx = (slot == 194 && live) ? 4 : 0;
        fx0 = 0.0f; hstep = 0.0f;
    }
    if (!live) npx = 0;
    col = min(col, W_IN - 1);                 // keep dead-thread loads in-bounds
    const int off_b = (col < W_IN - 1) ? 1 : 0;   // right-edge clamp: b == a

    // ---- targets early (latency hides under channel loads) ----
    const int rowbase = row * W_OUT;
    int tg[4];
    #pragma unroll
    for (int k = 0; k < 4; ++k)
        tg[k] = target[rowbase + min(xs_h + k, W_OUT - 1)];

    // ---- y-interp params ----
    float sy = fmaxf(fmaf((float)y + 0.5f, scl, -0.5f), 0.0f);
    int   y0 = min((int)sy, H_IN - 1);
    float fy = sy - (float)y0;
    int   y1 = min(y0 + 1, H_IN - 1);
    const int dy = (y1 - y0) * W_IN;

    const float* __restrict__ b1 = pred1 + (size_t)n * CHW_IN + y0 * W_IN + col;
    const float* __restrict__ b2 = pred2 + (size_t)n * CHW_IN + y0 * W_IN + col;

    float a_nv = 0.f;
    float a_w1 = 0.f, a_wlp1 = 0.f, a_cle1 = 0.f;
    float a_w2 = 0.f, a_wlp2 = 0.f, a_cle2 = 0.f;

    if (npx > 0) {
        // ---- softmax denominators: direct loads + incremental exponentials ----
        float s1[4] = {0.f, 0.f, 0.f, 0.f};
        float s2[4] = {0.f, 0.f, 0.f, 0.f};
        #pragma unroll
        for (int c = 0; c < C_CLS; ++c) {
            const float* q1 = b1 + c * HW_IN;
            const float* q2 = b2 + c * HW_IN;
            float a10 = q1[0], a11 = q1[off_b], a1L = q1[dy], a1H = q1[dy + off_b];
            float a20 = q2[0], a21 = q2[off_b], a2L = q2[dy], a2H = q2[dy + off_b];
            float lo1 = fmaf(fy, a1L - a10, a10);
            float hi1 = fmaf(fy, a1H - a11, a11);
            float lo2 = fmaf(fy, a2L - a20, a20);
            float hi2 = fmaf(fy, a2H - a21, a21);
            float d1 = hi1 - lo1, d2 = hi2 - lo2;
            float e1 = __expf(fmaf(fx0, d1, lo1));
            float e2 = __expf(fmaf(fx0, d2, lo2));
            float g1 = __expf(hstep * d1);
            float g2 = __expf(hstep * d2);
            #pragma unroll
            for (int k = 0; k < 4; ++k) {
                s1[k] += e1; e1 *= g1;
                s2[k] += e2; e2 *= g2;
            }
        }

        // ---- per-pixel epilogue; true-class texels re-loaded (L1-hot) ----
        #pragma unroll
        for (int k = 0; k < 4; ++k) {
            if (k < npx) {
                int t = tg[k];
                if (t != IGNORE_LBL) {
                    const float* q1 = b1 + t * HW_IN;
                    const float* q2 = b2 + t * HW_IN;
                    float u0 = fmaf(fy, q1[dy]         - q1[0],     q1[0]);
                    float u1 = fmaf(fy, q1[dy + off_b] - q1[off_b], q1[off_b]);
                    float v0 = fmaf(fy, q2[dy]         - q2[0],     q2[0]);
                    float v1 = fmaf(fy, q2[dy + off_b] - q2[off_b], q2[off_b]);
                    float fxk = fmaf((float)k, hstep, fx0);
                    float lt1 = fmaf(fxk, u1 - u0, u0);
                    float lt2 = fmaf(fxk, v1 - v0, v0);
                    float w   = c_class_w[t];
                    float nll1 = __logf(s1[k]) - lt1;
                    float nll2 = __logf(s2[k]) - lt2;
                    a_nv += 1.0f;

                    if (nll1 >= NLL_THR) {            // p1 <= 0.7 (common)
                        a_w1 += w; a_wlp1 = fmaf(w, nll1, a_wlp1); a_cle1 += 1.f;
                    } else {                          // rare: global hist
                        float p = __expf(-nll1);
                        int b = min(max((int)((p - 0.7f) * (109.f / 0.3f)), 0), NHI - 1);
                        atomicAdd(&ws[4 + b],   1.f);
                        atomicAdd(&ws[114 + b], w);
                        atomicAdd(&ws[224 + b], w * nll1);
                    }
                    if (nll2 >= NLL_THR) {            // p2 <= 0.7 (common)
                        a_w2 += w; a_wlp2 = fmaf(w, nll2, a_wlp2); a_cle2 += 1.f;
                    } else {
                        float p = __expf(-nll2);
                        int b = min(max((int)((p - 0.7f) * (109.f / 0.3f)), 0), NHI - 1);
                        atomicAdd(&ws[ACC_STRIDE + 4 + b],   1.f);
                        atomicAdd(&ws[ACC_STRIDE + 114 + b], w);
                        atomicAdd(&ws[ACC_STRIDE + 224 + b], w * nll2);
                    }
                }
            }
        }
    }

    // ---- wave butterfly reduce (7 vals) -> 7 striped atomics, no barrier ----
    #pragma unroll
    for (int off = 32; off > 0; off >>= 1) {
        a_nv   += __shfl_down(a_nv, off);
        a_w1   += __shfl_down(a_w1, off);
        a_wlp1 += __shfl_down(a_wlp1, off);
        a_cle1 += __shfl_down(a_cle1, off);
        a_w2   += __shfl_down(a_w2, off);
        a_wlp2 += __shfl_down(a_wlp2, off);
        a_cle2 += __shfl_down(a_cle2, off);
    }
    if (tid == 0) {
        float* acc = ws + SET_BASE + (blockIdx.x & (NSETS - 1)) * 16;
        atomicAdd(&acc[0], a_nv);
        atomicAdd(&acc[1], a_w1);
        atomicAdd(&acc[2], a_wlp1);
        atomicAdd(&acc[3], a_cle1);
        atomicAdd(&acc[4], a_w2);
        atomicAdd(&acc[5], a_wlp2);
        atomicAdd(&acc[6], a_cle2);
    }
}

__global__ void ohem_finalize(const float* __restrict__ ws, float* __restrict__ out)
{
    int lane = threadIdx.x;   // 0..63
    float v[7];
    #pragma unroll
    for (int k = 0; k < 7; ++k) v[k] = 0.f;
    #pragma unroll
    for (int g = 0; g < NSETS / 64; ++g) {
        const float* s = ws + SET_BASE + (lane + g * 64) * 16;
        #pragma unroll
        for (int k = 0; k < 7; ++k) v[k] += s[k];
    }
    #pragma unroll
    for (int off = 32; off > 0; off >>= 1) {
        #pragma unroll
        for (int k = 0; k < 7; ++k) v[k] += __shfl_down(v[k], off);
    }
    if (lane != 0) return;

    float nv = v[0];
    float loss[2];
    for (int pr = 0; pr < 2; ++pr) {
        const float* a = ws + pr * ACC_STRIDE;
        float sw   = pr ? v[4] : v[1];
        float swlp = pr ? v[5] : v[2];
        float cle  = pr ? v[6] : v[3];
        float l;
        if (nv <= (float)MIN_KEPT) {
            float tw = sw, twlp = swlp;
            for (int b = 0; b < NHI; ++b) { tw += a[114 + b]; twlp += a[224 + b]; }
            l = twlp / tw;
        } else if (cle >= (float)MIN_KEPT) {
            l = swlp / sw;
        } else {
            float cum = cle, tw = sw, twlp = swlp;
            for (int b = 0; b < NHI; ++b) {
                cum  += a[4 + b];
                tw   += a[114 + b];
                twlp += a[224 + b];
                if (cum >= (float)MIN_KEPT) break;
            }
            l = twlp / tw;
        }
        loss[pr] = l;
    }
    out[0] = 0.4f * loss[0] + loss[1];
}

extern "C" void kernel_launch(void* const* d_in, const int* in_sizes, int n_in,
                              void* d_out, int out_size, void* d_ws, size_t ws_size,
                              hipStream_t stream)
{
    const float* pred1  = (const float*)d_in[0];
    const float* pred2  = (const float*)d_in[1];
    const int*   target = (const int*)d_in[2];
    float* out = (float*)d_out;
    float* ws  = (float*)d_ws;

    hipMemsetAsync(d_ws, 0, (SET_BASE + NSETS * 16) * sizeof(float), stream);

    ohem_wave<<<dim3(NBLK), BLKT, 0, stream>>>(pred1, pred2, target, ws);
    ohem_finalize<<<1, 64, 0, stream>>>(ws, out);
}

// Round 12
// 55.378 us; speedup vs baseline: 2.3607x; 2.3607x over previous
//
#include <hip/hip_runtime.h>
#include <math.h>

#define C_CLS   19
#define H_IN    97
#define W_IN    97
#define HW_IN   (H_IN * W_IN)
#define CHW_IN  (C_CLS * HW_IN)
#define H_OUT   769
#define W_OUT   769
#define N_BATCH 4
#define NROWS   (N_BATCH * H_OUT)    // 3076
#define NSLOT_R 195                  // half-run slots per row (97*2 + 1 clamp)
#define TOTTHR  (NROWS * NSLOT_R)    // 599,820
#define BLKT    128                  // 2 waves; NO barriers, NO LDS
#define NBLK    ((TOTTHR + BLKT - 1) / BLKT)   // 4687
#define IGNORE_LBL 255
#define MIN_KEPT   100000
#define NHI     110
#define ACC_STRIDE 1024
#define NSETS   256                  // striped accumulator lines
#define SET_BASE 2048
#define NLL_THR 0.35667494f          // -ln(0.7)

__device__ const float c_class_w[C_CLS] = {
    0.8373f, 0.918f,  0.866f,  1.0345f, 1.0166f, 0.9969f, 0.9754f,
    1.0489f, 0.8786f, 1.0023f, 0.9539f, 0.9843f, 1.1116f, 0.9037f,
    1.0865f, 1.0955f, 1.0865f, 1.1529f, 1.0507f};

// ws layout (floats):
// [4..333] hist pred1 (cnt/sw/swnll, stride 110); [1028..1357] hist pred2
// [2048 + s*16 + k] striped set s (0=nv 1=w1 2=wlp1 3=cle1 4=w2 5=wlp2 6=cle2)

__global__ __launch_bounds__(BLKT) void ohem_wave(
    const float* __restrict__ pred1, const float* __restrict__ pred2,
    const int* __restrict__ target, float* __restrict__ ws)
{
    const int tid  = threadIdx.x;
    const int gtid = blockIdx.x * BLKT + tid;
    const bool live = gtid < TOTTHR;

    int row  = min(gtid / NSLOT_R, NROWS - 1);
    int slot = gtid - row * NSLOT_R;          // may exceed 194 only when !live
    const int n = row / H_OUT;
    const int y = row - n * H_OUT;

    const float scl = (float)H_IN / (float)H_OUT;

    // ---- half-run geometry ----
    int col, xs_h, npx;
    float fx0, hstep;
    if (slot < 194) {
        col = slot >> 1;
        int xs = ((2 * col + 1) * 769 + 96) / 194;
        int xe = min(((2 * col + 3) * 769 + 96) / 194, 769);
        int half = slot & 1;
        xs_h = xs + half * 4;
        npx  = half ? max(xe - xs - 4, 0) : min(xe - xs, 4);
        fx0  = fmaf((float)xs_h + 0.5f, scl, -0.5f) - (float)col;
        hstep = scl;
    } else {                                  // slot==194: left clamp, fx=0
        col = 0; xs_h = 0; npx = (slot == 194 && live) ? 4 : 0;
        fx0 = 0.0f; hstep = 0.0f;
    }
    if (!live) npx = 0;
    col = min(col, W_IN - 1);                 // keep dead-thread loads in-bounds
    const int off_b = (col < W_IN - 1) ? 1 : 0;   // right-edge clamp: b == a

    // ---- targets early (latency hides under channel loads) ----
    const int rowbase = row * W_OUT;
    int tg[4];
    #pragma unroll
    for (int k = 0; k < 4; ++k)
        tg[k] = target[rowbase + min(xs_h + k, W_OUT - 1)];

    // ---- y-interp params ----
    float sy = fmaxf(fmaf((float)y + 0.5f, scl, -0.5f), 0.0f);
    int   y0 = min((int)sy, H_IN - 1);
    float fy = sy - (float)y0;
    int   y1 = min(y0 + 1, H_IN - 1);
    const int dy = (y1 - y0) * W_IN;

    const float* __restrict__ b1 = pred1 + (size_t)n * CHW_IN + y0 * W_IN + col;
    const float* __restrict__ b2 = pred2 + (size_t)n * CHW_IN + y0 * W_IN + col;

    float a_nv = 0.f;
    float a_w1 = 0.f, a_wlp1 = 0.f, a_cle1 = 0.f;
    float a_w2 = 0.f, a_wlp2 = 0.f, a_cle2 = 0.f;

    if (npx > 0) {
        // ---- softmax denominators: direct loads + incremental exponentials ----
        float s1[4] = {0.f, 0.f, 0.f, 0.f};
        float s2[4] = {0.f, 0.f, 0.f, 0.f};
        #pragma unroll
        for (int c = 0; c < C_CLS; ++c) {
            const float* q1 = b1 + c * HW_IN;
            const float* q2 = b2 + c * HW_IN;
            float a10 = q1[0], a11 = q1[off_b], a1L = q1[dy], a1H = q1[dy + off_b];
            float a20 = q2[0], a21 = q2[off_b], a2L = q2[dy], a2H = q2[dy + off_b];
            float lo1 = fmaf(fy, a1L - a10, a10);
            float hi1 = fmaf(fy, a1H - a11, a11);
            float lo2 = fmaf(fy, a2L - a20, a20);
            float hi2 = fmaf(fy, a2H - a21, a21);
            float d1 = hi1 - lo1, d2 = hi2 - lo2;
            float e1 = __expf(fmaf(fx0, d1, lo1));
            float e2 = __expf(fmaf(fx0, d2, lo2));
            float g1 = __expf(hstep * d1);
            float g2 = __expf(hstep * d2);
            #pragma unroll
            for (int k = 0; k < 4; ++k) {
                s1[k] += e1; e1 *= g1;
                s2[k] += e2; e2 *= g2;
            }
        }

        // ---- per-pixel epilogue; true-class texels re-loaded (L1-hot) ----
        #pragma unroll
        for (int k = 0; k < 4; ++k) {
            if (k < npx) {
                int t = tg[k];
                if (t != IGNORE_LBL) {
                    const float* q1 = b1 + t * HW_IN;
                    const float* q2 = b2 + t * HW_IN;
                    float u0 = fmaf(fy, q1[dy]         - q1[0],     q1[0]);
                    float u1 = fmaf(fy, q1[dy + off_b] - q1[off_b], q1[off_b]);
                    float v0 = fmaf(fy, q2[dy]         - q2[0],     q2[0]);
                    float v1 = fmaf(fy, q2[dy + off_b] - q2[off_b], q2[off_b]);
                    float fxk = fmaf((float)k, hstep, fx0);
                    float lt1 = fmaf(fxk, u1 - u0, u0);
                    float lt2 = fmaf(fxk, v1 - v0, v0);
                    float w   = c_class_w[t];
                    float nll1 = __logf(s1[k]) - lt1;
                    float nll2 = __logf(s2[k]) - lt2;
                    a_nv += 1.0f;

                    if (nll1 >= NLL_THR) {            // p1 <= 0.7 (common)
                        a_w1 += w; a_wlp1 = fmaf(w, nll1, a_wlp1); a_cle1 += 1.f;
                    } else {                          // rare: global hist
                        float p = __expf(-nll1);
                        int b = min(max((int)((p - 0.7f) * (109.f / 0.3f)), 0), NHI - 1);
                        atomicAdd(&ws[4 + b],   1.f);
                        atomicAdd(&ws[114 + b], w);
                        atomicAdd(&ws[224 + b], w * nll1);
                    }
                    if (nll2 >= NLL_THR) {            // p2 <= 0.7 (common)
                        a_w2 += w; a_wlp2 = fmaf(w, nll2, a_wlp2); a_cle2 += 1.f;
                    } else {
                        float p = __expf(-nll2);
                        int b = min(max((int)((p - 0.7f) * (109.f / 0.3f)), 0), NHI - 1);
                        atomicAdd(&ws[ACC_STRIDE + 4 + b],   1.f);
                        atomicAdd(&ws[ACC_STRIDE + 114 + b], w);
                        atomicAdd(&ws[ACC_STRIDE + 224 + b], w * nll2);
                    }
                }
            }
        }
    }

    // ---- per-WAVE butterfly reduce -> 7 striped atomics (no LDS, no barrier) ----
    #pragma unroll
    for (int off = 32; off > 0; off >>= 1) {
        a_nv   += __shfl_down(a_nv, off);
        a_w1   += __shfl_down(a_w1, off);
        a_wlp1 += __shfl_down(a_wlp1, off);
        a_cle1 += __shfl_down(a_cle1, off);
        a_w2   += __shfl_down(a_w2, off);
        a_wlp2 += __shfl_down(a_wlp2, off);
        a_cle2 += __shfl_down(a_cle2, off);
    }
    if ((tid & 63) == 0) {
        int wave_id = blockIdx.x * (BLKT / 64) + (tid >> 6);
        float* acc = ws + SET_BASE + (wave_id & (NSETS - 1)) * 16;
        atomicAdd(&acc[0], a_nv);
        atomicAdd(&acc[1], a_w1);
        atomicAdd(&acc[2], a_wlp1);
        atomicAdd(&acc[3], a_cle1);
        atomicAdd(&acc[4], a_w2);
        atomicAdd(&acc[5], a_wlp2);
        atomicAdd(&acc[6], a_cle2);
    }
}

__global__ void ohem_finalize(const float* __restrict__ ws, float* __restrict__ out)
{
    int lane = threadIdx.x;   // 0..63
    float v[7];
    #pragma unroll
    for (int k = 0; k < 7; ++k) v[k] = 0.f;
    #pragma unroll
    for (int g = 0; g < NSETS / 64; ++g) {
        const float* s = ws + SET_BASE + (lane + g * 64) * 16;
        #pragma unroll
        for (int k = 0; k < 7; ++k) v[k] += s[k];
    }
    #pragma unroll
    for (int off = 32; off > 0; off >>= 1) {
        #pragma unroll
        for (int k = 0; k < 7; ++k) v[k] += __shfl_down(v[k], off);
    }
    if (lane != 0) return;

    float nv = v[0];
    float loss[2];
    for (int pr = 0; pr < 2; ++pr) {
        const float* a = ws + pr * ACC_STRIDE;
        float sw   = pr ? v[4] : v[1];
        float swlp = pr ? v[5] : v[2];
        float cle  = pr ? v[6] : v[3];
        float l;
        if (nv <= (float)MIN_KEPT) {
            float tw = sw, twlp = swlp;
            for (int b = 0; b < NHI; ++b) { tw += a[114 + b]; twlp += a[224 + b]; }
            l = twlp / tw;
        } else if (cle >= (float)MIN_KEPT) {
            l = swlp / sw;
        } else {
            float cum = cle, tw = sw, twlp = swlp;
            for (int b = 0; b < NHI; ++b) {
                cum  += a[4 + b];
                tw   += a[114 + b];
                twlp += a[224 + b];
                if (cum >= (float)MIN_KEPT) break;
            }
            l = twlp / tw;
        }
        loss[pr] = l;
    }
    out[0] = 0.4f * loss[0] + loss[1];
}

extern "C" void kernel_launch(void* const* d_in, const int* in_sizes, int n_in,
                              void* d_out, int out_size, void* d_ws, size_t ws_size,
                              hipStream_t stream)
{
    const float* pred1  = (const float*)d_in[0];
    const float* pred2  = (const float*)d_in[1];
    const int*   target = (const int*)d_in[2];
    float* out = (float*)d_out;
    float* ws  = (float*)d_ws;

    hipMemsetAsync(d_ws, 0, (SET_BASE + NSETS * 16) * sizeof(float), stream);

    ohem_wave<<<dim3(NBLK), BLKT, 0, stream>>>(pred1, pred2, target, ws);
    ohem_finalize<<<1, 64, 0, stream>>>(ws, out);
}

// Round 13
// 54.988 us; speedup vs baseline: 2.3774x; 1.0071x over previous
//
#include <hip/hip_runtime.h>
#include <math.h>

#define C_CLS   19
#define H_IN    97
#define W_IN    97
#define HW_IN   (H_IN * W_IN)
#define CHW_IN  (C_CLS * HW_IN)
#define H_OUT   769
#define W_OUT   769
#define N_BATCH 4
#define NROWS   (N_BATCH * H_OUT)    // 3076
#define NSLOT_R 195                  // half-run slots per row (97*2 + 1 clamp)
#define TOTTHR  (NROWS * NSLOT_R)    // 599,820
#define BLKT    256
#define NBLK    ((TOTTHR + BLKT - 1) / BLKT)   // 2344
#define IGNORE_LBL 255
#define MIN_KEPT   100000
#define NHI     110
#define ACC_STRIDE 1024
#define NSETS   256                  // striped accumulator lines
#define SET_BASE 2048
#define NLL_THR 0.35667494f          // -ln(0.7)

__device__ const float c_class_w[C_CLS] = {
    0.8373f, 0.918f,  0.866f,  1.0345f, 1.0166f, 0.9969f, 0.9754f,
    1.0489f, 0.8786f, 1.0023f, 0.9539f, 0.9843f, 1.1116f, 0.9037f,
    1.0865f, 1.0955f, 1.0865f, 1.1529f, 1.0507f};

// ws layout (floats):
// [4..333] hist pred1 (cnt/sw/swnll, stride 110); [1028..1357] hist pred2
// [2048 + s*16 + k] striped set s (0=nv 1=w1 2=wlp1 3=cle1 4=w2 5=wlp2 6=cle2)

// min-waves/EU = 1: let the allocator use VGPRs for load batching (ILP > TLP)
__global__ __launch_bounds__(BLKT, 1) void ohem_wave(
    const float* __restrict__ pred1, const float* __restrict__ pred2,
    const int* __restrict__ target, float* __restrict__ ws)
{
    const int tid  = threadIdx.x;
    const int gtid = blockIdx.x * BLKT + tid;
    const bool live = gtid < TOTTHR;

    int row  = min(gtid / NSLOT_R, NROWS - 1);
    int slot = gtid - row * NSLOT_R;          // may exceed 194 only when !live
    const int n = row / H_OUT;
    const int y = row - n * H_OUT;

    const float scl = (float)H_IN / (float)H_OUT;

    // ---- half-run geometry ----
    int col, xs_h, npx;
    float fx0, hstep;
    if (slot < 194) {
        col = slot >> 1;
        int xs = ((2 * col + 1) * 769 + 96) / 194;
        int xe = min(((2 * col + 3) * 769 + 96) / 194, 769);
        int half = slot & 1;
        xs_h = xs + half * 4;
        npx  = half ? max(xe - xs - 4, 0) : min(xe - xs, 4);
        fx0  = fmaf((float)xs_h + 0.5f, scl, -0.5f) - (float)col;
        hstep = scl;
    } else {                                  // slot==194: left clamp, fx=0
        col = 0; xs_h = 0; npx = (slot == 194 && live) ? 4 : 0;
        fx0 = 0.0f; hstep = 0.0f;
    }
    if (!live) npx = 0;
    col = min(col, W_IN - 1);                 // keep dead-thread loads in-bounds
    const int off_b = (col < W_IN - 1) ? 1 : 0;   // right-edge clamp: b == a

    // ---- targets early (latency hides under channel loads) ----
    const int rowbase = row * W_OUT;
    int tg[4];
    #pragma unroll
    for (int k = 0; k < 4; ++k)
        tg[k] = target[rowbase + min(xs_h + k, W_OUT - 1)];

    // ---- y-interp params ----
    float sy = fmaxf(fmaf((float)y + 0.5f, scl, -0.5f), 0.0f);
    int   y0 = min((int)sy, H_IN - 1);
    float fy = sy - (float)y0;
    int   y1 = min(y0 + 1, H_IN - 1);
    const int dy = (y1 - y0) * W_IN;

    const float* __restrict__ b1 = pred1 + (size_t)n * CHW_IN + y0 * W_IN + col;
    const float* __restrict__ b2 = pred2 + (size_t)n * CHW_IN + y0 * W_IN + col;

    float a_nv = 0.f;
    float a_w1 = 0.f, a_wlp1 = 0.f, a_cle1 = 0.f;
    float a_w2 = 0.f, a_wlp2 = 0.f, a_cle2 = 0.f;

    if (npx > 0) {
        float s1[4] = {0.f, 0.f, 0.f, 0.f};
        float s2[4] = {0.f, 0.f, 0.f, 0.f};

        // ---- channel loop in groups of 4: explicit load phase (32 scalar
        //      loads in flight) then math phase. ~5 latency exposures total
        //      instead of ~38 serialized ones. All indices static. ----
        #pragma unroll
        for (int cg = 0; cg < 5; ++cg) {
            const int c0 = cg * 4;
            const int cn = (cg == 4) ? 3 : 4;
            float t10[4], t11[4], t1L[4], t1H[4];
            float t20[4], t21[4], t2L[4], t2H[4];
            #pragma unroll
            for (int j = 0; j < cn; ++j) {
                const float* q1 = b1 + (c0 + j) * HW_IN;
                const float* q2 = b2 + (c0 + j) * HW_IN;
                t10[j] = q1[0];  t11[j] = q1[off_b];
                t1L[j] = q1[dy]; t1H[j] = q1[dy + off_b];
                t20[j] = q2[0];  t21[j] = q2[off_b];
                t2L[j] = q2[dy]; t2H[j] = q2[dy + off_b];
            }
            #pragma unroll
            for (int j = 0; j < cn; ++j) {
                float lo1 = fmaf(fy, t1L[j] - t10[j], t10[j]);
                float hi1 = fmaf(fy, t1H[j] - t11[j], t11[j]);
                float lo2 = fmaf(fy, t2L[j] - t20[j], t20[j]);
                float hi2 = fmaf(fy, t2H[j] - t21[j], t21[j]);
                float d1 = hi1 - lo1, d2 = hi2 - lo2;
                float e1 = __expf(fmaf(fx0, d1, lo1));
                float e2 = __expf(fmaf(fx0, d2, lo2));
                float g1 = __expf(hstep * d1);
                float g2 = __expf(hstep * d2);
                #pragma unroll
                for (int k = 0; k < 4; ++k) {
                    s1[k] += e1; e1 *= g1;
                    s2[k] += e2; e2 *= g2;
                }
            }
        }

        // ---- per-pixel epilogue; true-class texels re-loaded (L1-hot) ----
        #pragma unroll
        for (int k = 0; k < 4; ++k) {
            if (k < npx) {
                int t = tg[k];
                if (t != IGNORE_LBL) {
                    const float* q1 = b1 + t * HW_IN;
                    const float* q2 = b2 + t * HW_IN;
                    float u0 = fmaf(fy, q1[dy]         - q1[0],     q1[0]);
                    float u1 = fmaf(fy, q1[dy + off_b] - q1[off_b], q1[off_b]);
                    float v0 = fmaf(fy, q2[dy]         - q2[0],     q2[0]);
                    float v1 = fmaf(fy, q2[dy + off_b] - q2[off_b], q2[off_b]);
                    float fxk = fmaf((float)k, hstep, fx0);
                    float lt1 = fmaf(fxk, u1 - u0, u0);
                    float lt2 = fmaf(fxk, v1 - v0, v0);
                    float w   = c_class_w[t];
                    float nll1 = __logf(s1[k]) - lt1;
                    float nll2 = __logf(s2[k]) - lt2;
                    a_nv += 1.0f;

                    if (nll1 >= NLL_THR) {            // p1 <= 0.7 (common)
                        a_w1 += w; a_wlp1 = fmaf(w, nll1, a_wlp1); a_cle1 += 1.f;
                    } else {                          // rare: global hist
                        float p = __expf(-nll1);
                        int b = min(max((int)((p - 0.7f) * (109.f / 0.3f)), 0), NHI - 1);
                        atomicAdd(&ws[4 + b],   1.f);
                        atomicAdd(&ws[114 + b], w);
                        atomicAdd(&ws[224 + b], w * nll1);
                    }
                    if (nll2 >= NLL_THR) {            // p2 <= 0.7 (common)
                        a_w2 += w; a_wlp2 = fmaf(w, nll2, a_wlp2); a_cle2 += 1.f;
                    } else {
                        float p = __expf(-nll2);
                        int b = min(max((int)((p - 0.7f) * (109.f / 0.3f)), 0), NHI - 1);
                        atomicAdd(&ws[ACC_STRIDE + 4 + b],   1.f);
                        atomicAdd(&ws[ACC_STRIDE + 114 + b], w);
                        atomicAdd(&ws[ACC_STRIDE + 224 + b], w * nll2);
                    }
                }
            }
        }
    }

    // ---- per-WAVE butterfly reduce -> 7 striped atomics (no LDS barrier dep) ----
    #pragma unroll
    for (int off = 32; off > 0; off >>= 1) {
        a_nv   += __shfl_down(a_nv, off);
        a_w1   += __shfl_down(a_w1, off);
        a_wlp1 += __shfl_down(a_wlp1, off);
        a_cle1 += __shfl_down(a_cle1, off);
        a_w2   += __shfl_down(a_w2, off);
        a_wlp2 += __shfl_down(a_wlp2, off);
        a_cle2 += __shfl_down(a_cle2, off);
    }
    if ((tid & 63) == 0) {
        int wave_id = blockIdx.x * (BLKT / 64) + (tid >> 6);
        float* acc = ws + SET_BASE + (wave_id & (NSETS - 1)) * 16;
        atomicAdd(&acc[0], a_nv);
        atomicAdd(&acc[1], a_w1);
        atomicAdd(&acc[2], a_wlp1);
        atomicAdd(&acc[3], a_cle1);
        atomicAdd(&acc[4], a_w2);
        atomicAdd(&acc[5], a_wlp2);
        atomicAdd(&acc[6], a_cle2);
    }
}

__global__ void ohem_finalize(const float* __restrict__ ws, float* __restrict__ out)
{
    int lane = threadIdx.x;   // 0..63
    float v[7];
    #pragma unroll
    for (int k = 0; k < 7; ++k) v[k] = 0.f;
    #pragma unroll
    for (int g = 0; g < NSETS / 64; ++g) {
        const float* s = ws + SET_BASE + (lane + g * 64) * 16;
        #pragma unroll
        for (int k = 0; k < 7; ++k) v[k] += s[k];
    }
    #pragma unroll
    for (int off = 32; off > 0; off >>= 1) {
        #pragma unroll
        for (int k = 0; k < 7; ++k) v[k] += __shfl_down(v[k], off);
    }
    if (lane != 0) return;

    float nv = v[0];
    float loss[2];
    for (int pr = 0; pr < 2; ++pr) {
        const float* a = ws + pr * ACC_STRIDE;
        float sw   = pr ? v[4] : v[1];
        float swlp = pr ? v[5] : v[2];
        float cle  = pr ? v[6] : v[3];
        float l;
        if (nv <= (float)MIN_KEPT) {
            float tw = sw, twlp = swlp;
            for (int b = 0; b < NHI; ++b) { tw += a[114 + b]; twlp += a[224 + b]; }
            l = twlp / tw;
        } else if (cle >= (float)MIN_KEPT) {
            l = swlp / sw;
        } else {
            float cum = cle, tw = sw, twlp = swlp;
            for (int b = 0; b < NHI; ++b) {
                cum  += a[4 + b];
                tw   += a[114 + b];
                twlp += a[224 + b];
                if (cum >= (float)MIN_KEPT) break;
            }
            l = twlp / tw;
        }
        loss[pr] = l;
    }
    out[0] = 0.4f * loss[0] + loss[1];
}

extern "C" void kernel_launch(void* const* d_in, const int* in_sizes, int n_in,
                              void* d_out, int out_size, void* d_ws, size_t ws_size,
                              hipStream_t stream)
{
    const float* pred1  = (const float*)d_in[0];
    const float* pred2  = (const float*)d_in[1];
    const int*   target = (const int*)d_in[2];
    float* out = (float*)d_out;
    float* ws  = (float*)d_ws;

    hipMemsetAsync(d_ws, 0, (SET_BASE + NSETS * 16) * sizeof(float), stream);

    ohem_wave<<<dim3(NBLK), BLKT, 0, stream>>>(pred1, pred2, target, ws);
    ohem_finalize<<<1, 64, 0, stream>>>(ws, out);
}

// Round 14
// 37.020 us; speedup vs baseline: 3.5314x; 1.4854x over previous
//
#include <hip/hip_runtime.h>
#include <math.h>

#define C_CLS   19
#define H_IN    97
#define W_IN    97
#define HW_IN   (H_IN * W_IN)
#define CHW_IN  (C_CLS * HW_IN)
#define H_OUT   769
#define W_OUT   769
#define N_BATCH 4
#define NROWS   (N_BATCH * H_OUT)    // 3076
#define NXCD    8
#define IGNORE_LBL 255
#define MIN_KEPT   100000
#define NHI     110
#define ACC_STRIDE 1024
#define NSETS   64                   // striped accumulator sets (R4-proven)
#define SET_BASE 2048
#define NLL_THR 0.35667494f          // -ln(0.7)
#define ROWP    100                  // padded LDS row length (>= 98)
#define BLKT    128

__device__ const float c_class_w[C_CLS] = {
    0.8373f, 0.918f,  0.866f,  1.0345f, 1.0166f, 0.9969f, 0.9754f,
    1.0489f, 0.8786f, 1.0023f, 0.9539f, 0.9843f, 1.1116f, 0.9037f,
    1.0865f, 1.0955f, 1.0865f, 1.1529f, 1.0507f};

// ws layout (floats):
// [4..333]   hist pred1: cnt/sum_w/sum_wnll (stride 110)
// [1028..1357] hist pred2
// [2048 + s*16 + k] striped set s (0=nv 1=w1 2=wlp1 3=cle1 4=w2 5=wlp2 6=cle2)

__global__ __launch_bounds__(BLKT) void ohem_row(
    const float* __restrict__ pred1, const float* __restrict__ pred2,
    const int* __restrict__ target, float* __restrict__ ws)
{
    // ---- XCD-aware bijective row swizzle (m204 form) ----
    // HW round-robins consecutive blockIdx across the 8 XCDs. Map so each XCD
    // gets a CONTIGUOUS band of rows: its pred/target slab (~2.6 MB) fits the
    // per-XCD 4 MB L2, and the ~8 blocks sharing a source row co-locate.
    const int bid = blockIdx.x;
    const int xcd = bid & (NXCD - 1);
    const int idx = bid >> 3;
    // nwg=3076: q=384, r=4 -> first 4 XCDs get 385 rows, last 4 get 384
    const int q = NROWS / NXCD, r = NROWS % NXCD;
    const int row = (xcd < r ? xcd * (q + 1) : r * (q + 1) + (xcd - r) * q) + idx;

    const int n   = row / H_OUT;
    const int y   = row - n * H_OUT;
    const int tid = threadIdx.x;

    __shared__ float ry[2][C_CLS][ROWP];  // y-interpolated source rows
    __shared__ float wtab[C_CLS];
    __shared__ float sh_red[2][8];

    if (tid < C_CLS) wtab[tid] = c_class_w[tid];

    const float scl = (float)H_IN / (float)H_OUT;   // uniform fx step h

    // ---- column-run assignment (before staging, so target prefetch early) ----
    int col, xs, npx;
    float fx0, hstep;
    if (tid < 97) {
        col = tid;
        xs  = ((2 * tid + 1) * 769 + 96) / 194;
        int xe = min(((2 * tid + 3) * 769 + 96) / 194, 769);
        npx = xe - xs;                    // 7 or 8
        fx0 = fmaf((float)xs + 0.5f, scl, -0.5f) - (float)col;
        hstep = scl;
    } else if (tid == 97) {
        col = 0; xs = 0; npx = 4; fx0 = 0.0f; hstep = 0.0f;   // left clamp run
    } else {
        col = 0; xs = 0; npx = 0; fx0 = 0.0f; hstep = 0.0f;
    }

    // ---- prefetch this thread's targets (latency hides under staging) ----
    const int rowbase = (n * H_OUT + y) * W_OUT;
    int tg[8];
    #pragma unroll
    for (int k = 0; k < 8; ++k)
        tg[k] = target[rowbase + min(xs + k, W_OUT - 1)];

    // ---- y-interp params (uniform over row) ----
    float sy = fmaxf(fmaf((float)y + 0.5f, scl, -0.5f), 0.0f);
    int   y0 = min((int)sy, H_IN - 1);
    float fy = sy - (float)y0;
    int   y1 = min(y0 + 1, H_IN - 1);

    // ---- stage y-interpolated rows into LDS (coalesced; now L2-local) ----
    const float* __restrict__ b1 = pred1 + (size_t)n * CHW_IN;
    const float* __restrict__ b2 = pred2 + (size_t)n * CHW_IN;
    for (int j = tid; j < C_CLS * W_IN; j += BLKT) {
        int c = j / W_IN;
        int x = j - c * W_IN;
        int o0 = c * HW_IN + y0 * W_IN + x;
        int o1 = c * HW_IN + y1 * W_IN + x;
        float a0 = b1[o0], a1 = b1[o1];
        float c0 = b2[o0], c1 = b2[o1];
        float r1 = fmaf(fy, a1 - a0, a0);
        float r2 = fmaf(fy, c1 - c0, c0);
        ry[0][c][x] = r1;
        ry[1][c][x] = r2;
        if (x == W_IN - 1) {              // pad so col+1 read is safe & exact
            ry[0][c][W_IN] = r1;
            ry[1][c][W_IN] = r2;
        }
    }
    __syncthreads();

    // ---- softmax denominators: incremental exponentials along the run ----
    float s1[8], s2[8];
    #pragma unroll
    for (int k = 0; k < 8; ++k) { s1[k] = 0.f; s2[k] = 0.f; }

    #pragma unroll
    for (int c = 0; c < C_CLS; ++c) {
        float a1v = ry[0][c][col], b1v = ry[0][c][col + 1];
        float a2v = ry[1][c][col], b2v = ry[1][c][col + 1];
        float d1 = b1v - a1v;
        float d2 = b2v - a2v;
        float e1 = __expf(fmaf(fx0, d1, a1v));
        float e2 = __expf(fmaf(fx0, d2, a2v));
        float g1 = __expf(hstep * d1);
        float g2 = __expf(hstep * d2);
        #pragma unroll
        for (int k = 0; k < 8; ++k) {
            s1[k] += e1; e1 *= g1;
            s2[k] += e2; e2 *= g2;
        }
    }

    // ---- per-pixel epilogue ----
    float a_nv = 0.f;
    float a_w1 = 0.f, a_wlp1 = 0.f, a_cle1 = 0.f;
    float a_w2 = 0.f, a_wlp2 = 0.f, a_cle2 = 0.f;

    #pragma unroll
    for (int k = 0; k < 8; ++k) {
        if (k < npx) {
            int t = tg[k];
            if (t != IGNORE_LBL) {
                int ts = t;
                float fxk = fmaf((float)k, hstep, fx0);
                float u0 = ry[0][ts][col], u1 = ry[0][ts][col + 1];
                float v0 = ry[1][ts][col], v1 = ry[1][ts][col + 1];
                float lt1 = fmaf(fxk, u1 - u0, u0);
                float lt2 = fmaf(fxk, v1 - v0, v0);
                float w   = wtab[ts];
                float nll1 = __logf(s1[k]) - lt1;
                float nll2 = __logf(s2[k]) - lt2;
                a_nv += 1.0f;

                if (nll1 >= NLL_THR) {            // p1 <= 0.7 (common)
                    a_w1 += w; a_wlp1 = fmaf(w, nll1, a_wlp1); a_cle1 += 1.f;
                } else {                          // rare: direct global hist
                    float p = __expf(-nll1);
                    int b = min(max((int)((p - 0.7f) * (109.f / 0.3f)), 0), NHI - 1);
                    atomicAdd(&ws[4 + b],   1.f);
                    atomicAdd(&ws[114 + b], w);
                    atomicAdd(&ws[224 + b], w * nll1);
                }
                if (nll2 >= NLL_THR) {            // p2 <= 0.7 (common)
                    a_w2 += w; a_wlp2 = fmaf(w, nll2, a_wlp2); a_cle2 += 1.f;
                } else {
                    float p = __expf(-nll2);
                    int b = min(max((int)((p - 0.7f) * (109.f / 0.3f)), 0), NHI - 1);
                    atomicAdd(&ws[ACC_STRIDE + 4 + b],   1.f);
                    atomicAdd(&ws[ACC_STRIDE + 114 + b], w);
                    atomicAdd(&ws[ACC_STRIDE + 224 + b], w * nll2);
                }
            }
        }
    }

    // ---- wave butterfly reduce, 7 values ----
    #pragma unroll
    for (int off = 32; off > 0; off >>= 1) {
        a_nv   += __shfl_down(a_nv, off);
        a_w1   += __shfl_down(a_w1, off);
        a_wlp1 += __shfl_down(a_wlp1, off);
        a_cle1 += __shfl_down(a_cle1, off);
        a_w2   += __shfl_down(a_w2, off);
        a_wlp2 += __shfl_down(a_wlp2, off);
        a_cle2 += __shfl_down(a_cle2, off);
    }
    int lane = tid & 63;
    int wv   = tid >> 6;                   // 0..1
    if (lane == 0) {
        sh_red[wv][0] = a_nv;
        sh_red[wv][1] = a_w1; sh_red[wv][2] = a_wlp1; sh_red[wv][3] = a_cle1;
        sh_red[wv][4] = a_w2; sh_red[wv][5] = a_wlp2; sh_red[wv][6] = a_cle2;
    }
    __syncthreads();
    if (tid == 0) {
        float r[7] = {0, 0, 0, 0, 0, 0, 0};
        #pragma unroll
        for (int i = 0; i < 2; ++i)
            #pragma unroll
            for (int j = 0; j < 7; ++j) r[j] += sh_red[i][j];
        float* acc = ws + SET_BASE + (bid & (NSETS - 1)) * 16;
        #pragma unroll
        for (int j = 0; j < 7; ++j) atomicAdd(&acc[j], r[j]);
    }
}

__global__ void ohem_finalize(const float* __restrict__ ws, float* __restrict__ out)
{
    int lane = threadIdx.x;   // 0..63
    float v[7];
    #pragma unroll
    for (int k = 0; k < 7; ++k) v[k] = ws[SET_BASE + lane * 16 + k];
    #pragma unroll
    for (int off = 32; off > 0; off >>= 1) {
        #pragma unroll
        for (int k = 0; k < 7; ++k) v[k] += __shfl_down(v[k], off);
    }
    if (lane != 0) return;

    float nv = v[0];
    float loss[2];
    for (int pr = 0; pr < 2; ++pr) {
        const float* a = ws + pr * ACC_STRIDE;
        float sw   = pr ? v[4] : v[1];
        float swlp = pr ? v[5] : v[2];
        float cle  = pr ? v[6] : v[3];
        float l;
        if (nv <= (float)MIN_KEPT) {
            float tw = sw, twlp = swlp;
            for (int b = 0; b < NHI; ++b) { tw += a[114 + b]; twlp += a[224 + b]; }
            l = twlp / tw;
        } else if (cle >= (float)MIN_KEPT) {
            l = swlp / sw;
        } else {
            float cum = cle, tw = sw, twlp = swlp;
            for (int b = 0; b < NHI; ++b) {
                cum  += a[4 + b];
                tw   += a[114 + b];
                twlp += a[224 + b];
                if (cum >= (float)MIN_KEPT) break;
            }
            l = twlp / tw;
        }
        loss[pr] = l;
    }
    out[0] = 0.4f * loss[0] + loss[1];
}

extern "C" void kernel_launch(void* const* d_in, const int* in_sizes, int n_in,
                              void* d_out, int out_size, void* d_ws, size_t ws_size,
                              hipStream_t stream)
{
    const float* pred1  = (const float*)d_in[0];
    const float* pred2  = (const float*)d_in[1];
    const int*   target = (const int*)d_in[2];
    float* out = (float*)d_out;
    float* ws  = (float*)d_ws;

    hipMemsetAsync(d_ws, 0, (SET_BASE + NSETS * 16) * sizeof(float), stream);

    ohem_row<<<dim3(NROWS), BLKT, 0, stream>>>(pred1, pred2, target, ws);
    ohem_finalize<<<1, 64, 0, stream>>>(ws, out);
}